// Round 13
// baseline (707.600 us; speedup 1.0000x reference)
//
#include <hip/hip_runtime.h>
#include <hip/hip_bf16.h>

#define BB 4
#define TT 2048
#define SSZ 2048
#define DQq 512
#define NH 8
#define HDim 64

typedef __attribute__((ext_vector_type(8))) short short8;
typedef __attribute__((ext_vector_type(4))) float f32x4;

__device__ __forceinline__ short f2bf(float f) {
    union { float f; unsigned u; } v; v.f = f;
    unsigned r = v.u + 0x7fffu + ((v.u >> 16) & 1u);
    return (short)(r >> 16);
}

// ---------------- weight transpose + bf16 convert: W[Kd][512] -> Wt[512][Kd]
// (verified round 5)
__global__ void wt_kernel(const float* __restrict__ W, short* __restrict__ Wt, int Kd) {
    int tid = blockIdx.x * 256 + threadIdx.x;
    int n = tid / Kd, k = tid - n * Kd;
    Wt[tid] = f2bf(W[(size_t)k * DQq + n]);
}

// ---------------- projection GEMM (verified round 5, unchanged)
template<int MODE, bool IN_BF16>
__global__ __launch_bounds__(256) void gemm_proj(
    const void* __restrict__ Xv, const short* __restrict__ Wt,
    const float* __restrict__ bias, void* __restrict__ Out, int Kd)
{
    __shared__ short As[64 * 40];
    __shared__ short Bs[64 * 40];
    int tid = threadIdx.x;
    int wave = tid >> 6, lane = tid & 63;
    int g = lane >> 4, r = lane & 15;
    int wm = wave >> 1, wn = wave & 1;
    int m0 = blockIdx.x * 64, n0 = blockIdx.y * 64;

    const float* Xf = (const float*)Xv;
    const short* Xb = (const short*)Xv;

    f32x4 acc[2][2];
    for (int a = 0; a < 2; ++a) for (int b2 = 0; b2 < 2; ++b2) acc[a][b2] = (f32x4){0.f,0.f,0.f,0.f};

    int lrow = tid >> 2, lk = (tid & 3) * 8;

    for (int k0 = 0; k0 < Kd; k0 += 32) {
        short8 av;
        if (IN_BF16) {
            av = *(const short8*)(Xb + (size_t)(m0 + lrow) * Kd + k0 + lk);
        } else {
            const f32x4* p = (const f32x4*)(Xf + (size_t)(m0 + lrow) * Kd + k0 + lk);
            f32x4 x0 = p[0], x1 = p[1];
            av[0]=f2bf(x0[0]); av[1]=f2bf(x0[1]); av[2]=f2bf(x0[2]); av[3]=f2bf(x0[3]);
            av[4]=f2bf(x1[0]); av[5]=f2bf(x1[1]); av[6]=f2bf(x1[2]); av[7]=f2bf(x1[3]);
        }
        *(short8*)(As + lrow * 40 + lk) = av;
        short8 bv = *(const short8*)(Wt + (size_t)(n0 + lrow) * Kd + k0 + lk);
        *(short8*)(Bs + lrow * 40 + lk) = bv;
        __syncthreads();
        short8 af[2], bf[2];
        for (int mi = 0; mi < 2; ++mi)
            af[mi] = *(short8*)(As + (wm*32 + mi*16 + r) * 40 + g*8);
        for (int ni = 0; ni < 2; ++ni)
            bf[ni] = *(short8*)(Bs + (wn*32 + ni*16 + r) * 40 + g*8);
        for (int mi = 0; mi < 2; ++mi)
            for (int ni = 0; ni < 2; ++ni)
                acc[mi][ni] = __builtin_amdgcn_mfma_f32_16x16x32_bf16(af[mi], bf[ni], acc[mi][ni], 0, 0, 0);
        __syncthreads();
    }

    for (int mi = 0; mi < 2; ++mi)
      for (int ni = 0; ni < 2; ++ni)
        for (int i = 0; i < 4; ++i) {
            int m = m0 + wm*32 + mi*16 + g*4 + i;
            int n = n0 + wn*32 + ni*16 + r;
            float v = acc[mi][ni][i] + bias[n];
            if (MODE == 0) {
                int b = m >> 11, t = m & 2047, h = n >> 6, hd = n & 63;
                ((short*)Out)[((((size_t)b*NH + h)*TT + t) << 6) + hd] = f2bf(v);
            } else if (MODE == 1) {
                int b = m >> 11, t = m & 2047, h = n >> 6, hd = n & 63;
                ((short*)Out)[(((size_t)b*NH + h)*HDim + hd)*SSZ + t] = f2bf(v);
            } else {
                ((float*)Out)[(size_t)m * DQq + n] = v;
            }
        }
}

// ---------------- FUSED attention v3: 256-col chunks, 17 KB LDS -> 8 blocks/CU
// (occupancy 47% -> ~100%). Phase 2 writes w only to LDS; phase 3 stores attnW
// vectorized (f32x4) from the same LDS reads that feed PV. Values identical to v2.
#define WPITCH 260   // f32 row pitch; 260 mod 32 == 4 (round-10-verified bank pattern)

__global__ __launch_bounds__(256) void attn_pv(
    const short* __restrict__ Q, const short* __restrict__ K,
    const short* __restrict__ Vt,
    const int* __restrict__ kpm, const float* __restrict__ amask,
    float* __restrict__ attnW, float* __restrict__ AO)
{
    __shared__ float s_wl[4][16];
    __shared__ float s_li[16];
    __shared__ float wch[16][WPITCH];

    int tid = threadIdx.x;
    int wave = tid >> 6, lane = tid & 63;
    int g = lane >> 4, r = lane & 15;
    int t0 = blockIdx.x * 16;
    int bh = blockIdx.y;
    int b = bh >> 3, h = bh & 7;

    const short* Qp = Q + ((size_t)bh * TT + t0) * HDim;
    const short* Kp = K + (size_t)bh * SSZ * HDim;

    short8 qf0 = *(const short8*)(Qp + r * HDim + g * 8);
    short8 qf1 = *(const short8*)(Qp + r * HDim + 32 + g * 8);

    // ---- phase 1: denominator only (no-max exp; verified r12)
    int ws0 = wave * 512;
    float lrun[4] = {0.f, 0.f, 0.f, 0.f};
    for (int c = 0; c < 32; ++c) {
        int s_idx = ws0 + c * 16 + r;
        short8 kf0 = *(const short8*)(Kp + (size_t)s_idx * HDim + g * 8);
        short8 kf1 = *(const short8*)(Kp + (size_t)s_idx * HDim + 32 + g * 8);
        f32x4 sc = (f32x4){0.f,0.f,0.f,0.f};
        sc = __builtin_amdgcn_mfma_f32_16x16x32_bf16(qf0, kf0, sc, 0, 0, 0);
        sc = __builtin_amdgcn_mfma_f32_16x16x32_bf16(qf1, kf1, sc, 0, 0, 0);
        int ok = kpm[b * SSZ + s_idx];
        for (int i = 0; i < 4; ++i) {
            float v = sc[i] * 0.125f + amask[(size_t)(t0 + g*4 + i) * SSZ + s_idx];
            if (!ok) v = -1e30f;
            lrun[i] += __expf(v);
        }
    }
    for (int i = 0; i < 4; ++i)
        for (int off = 1; off < 16; off <<= 1)
            lrun[i] += __shfl_xor(lrun[i], off);
    if (r == 0)
        for (int i = 0; i < 4; ++i) s_wl[wave][g * 4 + i] = lrun[i];
    __syncthreads();
    if (tid < 16)
        s_li[tid] = 1.0f / (s_wl[0][tid] + s_wl[1][tid] + s_wl[2][tid] + s_wl[3][tid]);
    __syncthreads();

    float lr[4];
    for (int i = 0; i < 4; ++i) lr[i] = s_li[g * 4 + i];

    const short* vrow = Vt + ((size_t)bh * HDim + wave * 16 + r) * SSZ;
    float* wrowg = attnW + ((size_t)bh * TT + t0 + r) * SSZ;
    f32x4 oacc = (f32x4){0.f, 0.f, 0.f, 0.f};

    // ---- phases 2+3 interleaved per 256-col chunk
    for (int ch = 0; ch < 8; ++ch) {
        // phase 2: each wave computes a 64-col slice; w -> LDS only
        int base_w = ch * 256 + wave * 64;
        for (int c2 = 0; c2 < 4; ++c2) {
            int s_idx = base_w + c2 * 16 + r;
            short8 kf0 = *(const short8*)(Kp + (size_t)s_idx * HDim + g * 8);
            short8 kf1 = *(const short8*)(Kp + (size_t)s_idx * HDim + 32 + g * 8);
            f32x4 sc = (f32x4){0.f,0.f,0.f,0.f};
            sc = __builtin_amdgcn_mfma_f32_16x16x32_bf16(qf0, kf0, sc, 0, 0, 0);
            sc = __builtin_amdgcn_mfma_f32_16x16x32_bf16(qf1, kf1, sc, 0, 0, 0);
            int ok = kpm[b * SSZ + s_idx];
            for (int i = 0; i < 4; ++i) {
                float v = sc[i] * 0.125f + amask[(size_t)(t0 + g*4 + i) * SSZ + s_idx];
                if (!ok) v = -1e30f;
                wch[g*4 + i][wave * 64 + c2 * 16 + r] = __expf(v) * lr[i];
            }
        }
        __syncthreads();   // wch complete for this chunk

        // phase 3: vectorized attnW store + PV (r10-verified gather + MFMA)
        #pragma unroll
        for (int s = 0; s < 8; ++s) {
            const float* wp = &wch[r][s * 32 + g * 8];
            f32x4 w0 = *(const f32x4*)wp;
            f32x4 w1 = *(const f32x4*)(wp + 4);
            *(f32x4*)(wrowg + ch * 256 + s * 32 + g * 8) = w0;
            *(f32x4*)(wrowg + ch * 256 + s * 32 + g * 8 + 4) = w1;
            short8 wf;
            wf[0]=f2bf(w0[0]); wf[1]=f2bf(w0[1]); wf[2]=f2bf(w0[2]); wf[3]=f2bf(w0[3]);
            wf[4]=f2bf(w1[0]); wf[5]=f2bf(w1[1]); wf[6]=f2bf(w1[2]); wf[7]=f2bf(w1[3]);
            short8 vf = *(const short8*)(vrow + ch * 256 + s * 32 + g * 8);
            oacc = __builtin_amdgcn_mfma_f32_16x16x32_bf16(wf, vf, oacc, 0, 0, 0);
        }
        __syncthreads();   // wch reads done before next chunk overwrites
    }

    // C/D: oacc[i] = PV[t = g*4+i][hd-local = r]; hd = wave*16 + r (verified r8)
    for (int i = 0; i < 4; ++i)
        AO[((size_t)(b * TT + t0 + g*4 + i)) * DQq + h * HDim + wave * 16 + r] = oacc[i];
}

extern "C" void kernel_launch(void* const* d_in, const int* in_sizes, int n_in,
                              void* d_out, int out_size, void* d_ws, size_t ws_size,
                              hipStream_t stream)
{
    const float* query = (const float*)d_in[0];
    const float* key   = (const float*)d_in[1];
    const float* value = (const float*)d_in[2];
    const int*   kpm   = (const int*)d_in[3];
    const float* amask = (const float*)d_in[4];
    const float* Wq = (const float*)d_in[5];
    const float* bq = (const float*)d_in[6];
    const float* Wk = (const float*)d_in[7];
    const float* bk = (const float*)d_in[8];
    const float* Wv = (const float*)d_in[9];
    const float* bv = (const float*)d_in[10];
    const float* Wo = (const float*)d_in[11];
    const float* bo = (const float*)d_in[12];

    char* ws = (char*)d_ws;
    short* WqT = (short*)ws;  ws += (size_t)512 * 512 * 2;
    short* WkT = (short*)ws;  ws += (size_t)512 * 1024 * 2;
    short* WvT = (short*)ws;  ws += (size_t)512 * 1024 * 2;
    short* WoT = (short*)ws;  ws += (size_t)512 * 512 * 2;
    short* Qh  = (short*)ws;  ws += (size_t)BB * NH * TT * HDim * 2;
    short* Kh  = (short*)ws;  ws += (size_t)BB * NH * SSZ * HDim * 2;
    short* Vth = (short*)ws;  ws += (size_t)BB * NH * HDim * SSZ * 2;
    float* AOf = (float*)ws;  ws += (size_t)BB * TT * DQq * 4;

    float* out0  = (float*)d_out;
    float* attnW = out0 + (size_t)BB * TT * DQq;

    wt_kernel<<<(512*512)/256, 256, 0, stream>>>(Wq, WqT, 512);
    wt_kernel<<<(1024*512)/256, 256, 0, stream>>>(Wk, WkT, 1024);
    wt_kernel<<<(1024*512)/256, 256, 0, stream>>>(Wv, WvT, 1024);
    wt_kernel<<<(512*512)/256, 256, 0, stream>>>(Wo, WoT, 512);

    dim3 gp(8192 / 64, 512 / 64);
    gemm_proj<0, false><<<gp, 256, 0, stream>>>(query, WqT, bq, Qh, 512);
    gemm_proj<0, false><<<gp, 256, 0, stream>>>(key,   WkT, bk, Kh, 1024);
    gemm_proj<1, false><<<gp, 256, 0, stream>>>(value, WvT, bv, Vth, 1024);

    dim3 ga(TT / 16, BB * NH);
    attn_pv<<<ga, 256, 0, stream>>>(Qh, Kh, Vth, kpm, amask, attnW, AOf);

    gemm_proj<2, false><<<gp, 256, 0, stream>>>(AOf, WoT, bo, out0, 512);
}

// Round 14
// 642.590 us; speedup vs baseline: 1.1012x; 1.1012x over previous
//
#include <hip/hip_runtime.h>
#include <hip/hip_bf16.h>

#define BB 4
#define TT 2048
#define SSZ 2048
#define DQq 512
#define NH 8
#define HDim 64

typedef __attribute__((ext_vector_type(8))) short short8;
typedef __attribute__((ext_vector_type(4))) float f32x4;
typedef __attribute__((ext_vector_type(4))) int i32x4;

__device__ __forceinline__ short f2bf(float f) {
    union { float f; unsigned u; } v; v.f = f;
    unsigned r = v.u + 0x7fffu + ((v.u >> 16) & 1u);
    return (short)(r >> 16);
}

// ---------------- weight transpose + bf16 convert: W[Kd][512] -> Wt[512][Kd]
// (verified round 5)
__global__ void wt_kernel(const float* __restrict__ W, short* __restrict__ Wt, int Kd) {
    int tid = blockIdx.x * 256 + threadIdx.x;
    int n = tid / Kd, k = tid - n * Kd;
    Wt[tid] = f2bf(W[(size_t)k * DQq + n]);
}

// ---------------- projection GEMM (verified round 5, unchanged)
template<int MODE, bool IN_BF16>
__global__ __launch_bounds__(256) void gemm_proj(
    const void* __restrict__ Xv, const short* __restrict__ Wt,
    const float* __restrict__ bias, void* __restrict__ Out, int Kd)
{
    __shared__ short As[64 * 40];
    __shared__ short Bs[64 * 40];
    int tid = threadIdx.x;
    int wave = tid >> 6, lane = tid & 63;
    int g = lane >> 4, r = lane & 15;
    int wm = wave >> 1, wn = wave & 1;
    int m0 = blockIdx.x * 64, n0 = blockIdx.y * 64;

    const float* Xf = (const float*)Xv;
    const short* Xb = (const short*)Xv;

    f32x4 acc[2][2];
    for (int a = 0; a < 2; ++a) for (int b2 = 0; b2 < 2; ++b2) acc[a][b2] = (f32x4){0.f,0.f,0.f,0.f};

    int lrow = tid >> 2, lk = (tid & 3) * 8;

    for (int k0 = 0; k0 < Kd; k0 += 32) {
        short8 av;
        if (IN_BF16) {
            av = *(const short8*)(Xb + (size_t)(m0 + lrow) * Kd + k0 + lk);
        } else {
            const f32x4* p = (const f32x4*)(Xf + (size_t)(m0 + lrow) * Kd + k0 + lk);
            f32x4 x0 = p[0], x1 = p[1];
            av[0]=f2bf(x0[0]); av[1]=f2bf(x0[1]); av[2]=f2bf(x0[2]); av[3]=f2bf(x0[3]);
            av[4]=f2bf(x1[0]); av[5]=f2bf(x1[1]); av[6]=f2bf(x1[2]); av[7]=f2bf(x1[3]);
        }
        *(short8*)(As + lrow * 40 + lk) = av;
        short8 bv = *(const short8*)(Wt + (size_t)(n0 + lrow) * Kd + k0 + lk);
        *(short8*)(Bs + lrow * 40 + lk) = bv;
        __syncthreads();
        short8 af[2], bf[2];
        for (int mi = 0; mi < 2; ++mi)
            af[mi] = *(short8*)(As + (wm*32 + mi*16 + r) * 40 + g*8);
        for (int ni = 0; ni < 2; ++ni)
            bf[ni] = *(short8*)(Bs + (wn*32 + ni*16 + r) * 40 + g*8);
        for (int mi = 0; mi < 2; ++mi)
            for (int ni = 0; ni < 2; ++ni)
                acc[mi][ni] = __builtin_amdgcn_mfma_f32_16x16x32_bf16(af[mi], bf[ni], acc[mi][ni], 0, 0, 0);
        __syncthreads();
    }

    for (int mi = 0; mi < 2; ++mi)
      for (int ni = 0; ni < 2; ++ni)
        for (int i = 0; i < 4; ++i) {
            int m = m0 + wm*32 + mi*16 + g*4 + i;
            int n = n0 + wn*32 + ni*16 + r;
            float v = acc[mi][ni][i] + bias[n];
            if (MODE == 0) {
                int b = m >> 11, t = m & 2047, h = n >> 6, hd = n & 63;
                ((short*)Out)[((((size_t)b*NH + h)*TT + t) << 6) + hd] = f2bf(v);
            } else if (MODE == 1) {
                int b = m >> 11, t = m & 2047, h = n >> 6, hd = n & 63;
                ((short*)Out)[(((size_t)b*NH + h)*HDim + hd)*SSZ + t] = f2bf(v);
            } else {
                ((float*)Out)[(size_t)m * DQq + n] = v;
            }
        }
}

// ---------------- FUSED attention v4: TRANSPOSED QK^T (mfma(K,Q) -> S^T) so
// each lane owns one t-row => amask/kpm loads, attnW stores, and wch writes
// are all f32x4/i32x4 vectorized. Phase 3 PV and AO epilogue = r12 verbatim.
#define WPITCH 516   // f32 row pitch (512-chunk), r12-verified read pattern

__global__ __launch_bounds__(256) void attn_pv(
    const short* __restrict__ Q, const short* __restrict__ K,
    const short* __restrict__ Vt,
    const int* __restrict__ kpm, const float* __restrict__ amask,
    float* __restrict__ attnW, float* __restrict__ AO)
{
    __shared__ float s_wl[4][16];
    __shared__ float s_li[16];
    __shared__ float wch[16][WPITCH];

    int tid = threadIdx.x;
    int wave = tid >> 6, lane = tid & 63;
    int g = lane >> 4, r = lane & 15;
    int t0 = blockIdx.x * 16;
    int bh = blockIdx.y;
    int b = bh >> 3, h = bh & 7;

    const short* Qp = Q + ((size_t)bh * TT + t0) * HDim;
    const short* Kp = K + (size_t)bh * SSZ * HDim;

    short8 qf0 = *(const short8*)(Qp + r * HDim + g * 8);
    short8 qf1 = *(const short8*)(Qp + r * HDim + 32 + g * 8);

    const float* amrow = amask + (size_t)(t0 + r) * SSZ;
    const int*   kpmb  = kpm + b * SSZ;

    // ---- phase 1 (transposed): denominator. lane accumulates cols for row t0+r.
    int ws0 = wave * 512;
    float lrun = 0.f;
    for (int it = 0; it < 16; ++it) {
        int col0 = ws0 + it * 32;
        short8 kA0 = *(const short8*)(Kp + (size_t)(col0 + r) * HDim + g * 8);
        short8 kA1 = *(const short8*)(Kp + (size_t)(col0 + r) * HDim + 32 + g * 8);
        short8 kB0 = *(const short8*)(Kp + (size_t)(col0 + 16 + r) * HDim + g * 8);
        short8 kB1 = *(const short8*)(Kp + (size_t)(col0 + 16 + r) * HDim + 32 + g * 8);
        f32x4 scA = (f32x4){0.f,0.f,0.f,0.f}, scB = (f32x4){0.f,0.f,0.f,0.f};
        scA = __builtin_amdgcn_mfma_f32_16x16x32_bf16(kA0, qf0, scA, 0, 0, 0);
        scA = __builtin_amdgcn_mfma_f32_16x16x32_bf16(kA1, qf1, scA, 0, 0, 0);
        scB = __builtin_amdgcn_mfma_f32_16x16x32_bf16(kB0, qf0, scB, 0, 0, 0);
        scB = __builtin_amdgcn_mfma_f32_16x16x32_bf16(kB1, qf1, scB, 0, 0, 0);
        // lane(g,r): scA[i] = S[t0+r][col0+g*4+i], scB[i] = S[t0+r][col0+16+g*4+i]
        f32x4 amA = *(const f32x4*)(amrow + col0 + g * 4);
        f32x4 amB = *(const f32x4*)(amrow + col0 + 16 + g * 4);
        i32x4 okA = *(const i32x4*)(kpmb + col0 + g * 4);
        i32x4 okB = *(const i32x4*)(kpmb + col0 + 16 + g * 4);
        for (int i = 0; i < 4; ++i) {
            float vA = scA[i] * 0.125f + amA[i];
            if (okA[i] == 0) vA = -1e30f;
            lrun += __expf(vA);
            float vB = scB[i] * 0.125f + amB[i];
            if (okB[i] == 0) vB = -1e30f;
            lrun += __expf(vB);
        }
    }
    // row-sum reduce across the 4 g-groups of this wave
    lrun += __shfl_xor(lrun, 16);
    lrun += __shfl_xor(lrun, 32);
    if (lane < 16) s_wl[wave][lane] = lrun;
    __syncthreads();
    if (tid < 16)
        s_li[tid] = 1.0f / (s_wl[0][tid] + s_wl[1][tid] + s_wl[2][tid] + s_wl[3][tid]);
    __syncthreads();

    float li_r = s_li[r];
    const short* vrow = Vt + ((size_t)bh * HDim + wave * 16 + r) * SSZ;
    float* wrowT = attnW + ((size_t)bh * TT + t0 + r) * SSZ;
    f32x4 oacc = (f32x4){0.f, 0.f, 0.f, 0.f};

    // ---- phases 2+3 per 512-col chunk (r12 chunking)
    for (int ch = 0; ch < 4; ++ch) {
        // phase 2 (transposed): wave computes its 128-col slice; vectorized
        // stores to attnW global + LDS wch (r12 layout)
        for (int it = 0; it < 4; ++it) {
            int col0 = ch * 512 + wave * 128 + it * 32;
            short8 kA0 = *(const short8*)(Kp + (size_t)(col0 + r) * HDim + g * 8);
            short8 kA1 = *(const short8*)(Kp + (size_t)(col0 + r) * HDim + 32 + g * 8);
            short8 kB0 = *(const short8*)(Kp + (size_t)(col0 + 16 + r) * HDim + g * 8);
            short8 kB1 = *(const short8*)(Kp + (size_t)(col0 + 16 + r) * HDim + 32 + g * 8);
            f32x4 scA = (f32x4){0.f,0.f,0.f,0.f}, scB = (f32x4){0.f,0.f,0.f,0.f};
            scA = __builtin_amdgcn_mfma_f32_16x16x32_bf16(kA0, qf0, scA, 0, 0, 0);
            scA = __builtin_amdgcn_mfma_f32_16x16x32_bf16(kA1, qf1, scA, 0, 0, 0);
            scB = __builtin_amdgcn_mfma_f32_16x16x32_bf16(kB0, qf0, scB, 0, 0, 0);
            scB = __builtin_amdgcn_mfma_f32_16x16x32_bf16(kB1, qf1, scB, 0, 0, 0);
            f32x4 amA = *(const f32x4*)(amrow + col0 + g * 4);
            f32x4 amB = *(const f32x4*)(amrow + col0 + 16 + g * 4);
            i32x4 okA = *(const i32x4*)(kpmb + col0 + g * 4);
            i32x4 okB = *(const i32x4*)(kpmb + col0 + 16 + g * 4);
            f32x4 wA, wB;
            for (int i = 0; i < 4; ++i) {
                float vA = scA[i] * 0.125f + amA[i];
                if (okA[i] == 0) vA = -1e30f;
                wA[i] = __expf(vA) * li_r;
                float vB = scB[i] * 0.125f + amB[i];
                if (okB[i] == 0) vB = -1e30f;
                wB[i] = __expf(vB) * li_r;
            }
            *(f32x4*)(wrowT + col0 + g * 4) = wA;
            *(f32x4*)(wrowT + col0 + 16 + g * 4) = wB;
            int lcol = wave * 128 + it * 32;
            *(f32x4*)&wch[r][lcol + g * 4] = wA;
            *(f32x4*)&wch[r][lcol + 16 + g * 4] = wB;
        }
        __syncthreads();   // wch complete for this chunk

        // phase 3: PV (r12-verified gather + MFMA)
        #pragma unroll
        for (int s = 0; s < 16; ++s) {
            const float* wp = &wch[r][s * 32 + g * 8];
            f32x4 w0 = *(const f32x4*)wp;
            f32x4 w1 = *(const f32x4*)(wp + 4);
            short8 wf;
            wf[0]=f2bf(w0[0]); wf[1]=f2bf(w0[1]); wf[2]=f2bf(w0[2]); wf[3]=f2bf(w0[3]);
            wf[4]=f2bf(w1[0]); wf[5]=f2bf(w1[1]); wf[6]=f2bf(w1[2]); wf[7]=f2bf(w1[3]);
            short8 vf = *(const short8*)(vrow + ch * 512 + s * 32 + g * 8);
            oacc = __builtin_amdgcn_mfma_f32_16x16x32_bf16(wf, vf, oacc, 0, 0, 0);
        }
        __syncthreads();   // wch reads done before next chunk overwrites
    }

    // C/D: oacc[i] = PV[t = g*4+i][hd-local = r]; hd = wave*16 + r (verified r8)
    for (int i = 0; i < 4; ++i)
        AO[((size_t)(b * TT + t0 + g*4 + i)) * DQq + h * HDim + wave * 16 + r] = oacc[i];
}

extern "C" void kernel_launch(void* const* d_in, const int* in_sizes, int n_in,
                              void* d_out, int out_size, void* d_ws, size_t ws_size,
                              hipStream_t stream)
{
    const float* query = (const float*)d_in[0];
    const float* key   = (const float*)d_in[1];
    const float* value = (const float*)d_in[2];
    const int*   kpm   = (const int*)d_in[3];
    const float* amask = (const float*)d_in[4];
    const float* Wq = (const float*)d_in[5];
    const float* bq = (const float*)d_in[6];
    const float* Wk = (const float*)d_in[7];
    const float* bk = (const float*)d_in[8];
    const float* Wv = (const float*)d_in[9];
    const float* bv = (const float*)d_in[10];
    const float* Wo = (const float*)d_in[11];
    const float* bo = (const float*)d_in[12];

    char* ws = (char*)d_ws;
    short* WqT = (short*)ws;  ws += (size_t)512 * 512 * 2;
    short* WkT = (short*)ws;  ws += (size_t)512 * 1024 * 2;
    short* WvT = (short*)ws;  ws += (size_t)512 * 1024 * 2;
    short* WoT = (short*)ws;  ws += (size_t)512 * 512 * 2;
    short* Qh  = (short*)ws;  ws += (size_t)BB * NH * TT * HDim * 2;
    short* Kh  = (short*)ws;  ws += (size_t)BB * NH * SSZ * HDim * 2;
    short* Vth = (short*)ws;  ws += (size_t)BB * NH * HDim * SSZ * 2;
    float* AOf = (float*)ws;  ws += (size_t)BB * TT * DQq * 4;

    float* out0  = (float*)d_out;
    float* attnW = out0 + (size_t)BB * TT * DQq;

    wt_kernel<<<(512*512)/256, 256, 0, stream>>>(Wq, WqT, 512);
    wt_kernel<<<(1024*512)/256, 256, 0, stream>>>(Wk, WkT, 1024);
    wt_kernel<<<(1024*512)/256, 256, 0, stream>>>(Wv, WvT, 1024);
    wt_kernel<<<(512*512)/256, 256, 0, stream>>>(Wo, WoT, 512);

    dim3 gp(8192 / 64, 512 / 64);
    gemm_proj<0, false><<<gp, 256, 0, stream>>>(query, WqT, bq, Qh, 512);
    gemm_proj<0, false><<<gp, 256, 0, stream>>>(key,   WkT, bk, Kh, 1024);
    gemm_proj<1, false><<<gp, 256, 0, stream>>>(value, WvT, bv, Vth, 1024);

    dim3 ga(TT / 16, BB * NH);
    attn_pv<<<ga, 256, 0, stream>>>(Qh, Kh, Vth, kpm, amask, attnW, AOf);

    gemm_proj<2, false><<<gp, 256, 0, stream>>>(AOf, WoT, bo, out0, 512);
}

// Round 15
// 469.724 us; speedup vs baseline: 1.5064x; 1.3680x over previous
//
#include <hip/hip_runtime.h>
#include <hip/hip_bf16.h>

#define BB 4
#define TT 2048
#define SSZ 2048
#define DQq 512
#define NH 8
#define HDim 64

typedef __attribute__((ext_vector_type(8))) short short8;
typedef __attribute__((ext_vector_type(4))) float f32x4;
typedef __attribute__((ext_vector_type(4))) int i32x4;

__device__ __forceinline__ short f2bf(float f) {
    union { float f; unsigned u; } v; v.f = f;
    unsigned r = v.u + 0x7fffu + ((v.u >> 16) & 1u);
    return (short)(r >> 16);
}

// ---------------- weight transpose + bf16 convert: W[Kd][512] -> Wt[512][Kd]
// (verified round 5)
__global__ void wt_kernel(const float* __restrict__ W, short* __restrict__ Wt, int Kd) {
    int tid = blockIdx.x * 256 + threadIdx.x;
    int n = tid / Kd, k = tid - n * Kd;
    Wt[tid] = f2bf(W[(size_t)k * DQq + n]);
}

// ---------------- projection GEMM (verified round 5, unchanged)
template<int MODE, bool IN_BF16>
__global__ __launch_bounds__(256) void gemm_proj(
    const void* __restrict__ Xv, const short* __restrict__ Wt,
    const float* __restrict__ bias, void* __restrict__ Out, int Kd)
{
    __shared__ short As[64 * 40];
    __shared__ short Bs[64 * 40];
    int tid = threadIdx.x;
    int wave = tid >> 6, lane = tid & 63;
    int g = lane >> 4, r = lane & 15;
    int wm = wave >> 1, wn = wave & 1;
    int m0 = blockIdx.x * 64, n0 = blockIdx.y * 64;

    const float* Xf = (const float*)Xv;
    const short* Xb = (const short*)Xv;

    f32x4 acc[2][2];
    for (int a = 0; a < 2; ++a) for (int b2 = 0; b2 < 2; ++b2) acc[a][b2] = (f32x4){0.f,0.f,0.f,0.f};

    int lrow = tid >> 2, lk = (tid & 3) * 8;

    for (int k0 = 0; k0 < Kd; k0 += 32) {
        short8 av;
        if (IN_BF16) {
            av = *(const short8*)(Xb + (size_t)(m0 + lrow) * Kd + k0 + lk);
        } else {
            const f32x4* p = (const f32x4*)(Xf + (size_t)(m0 + lrow) * Kd + k0 + lk);
            f32x4 x0 = p[0], x1 = p[1];
            av[0]=f2bf(x0[0]); av[1]=f2bf(x0[1]); av[2]=f2bf(x0[2]); av[3]=f2bf(x0[3]);
            av[4]=f2bf(x1[0]); av[5]=f2bf(x1[1]); av[6]=f2bf(x1[2]); av[7]=f2bf(x1[3]);
        }
        *(short8*)(As + lrow * 40 + lk) = av;
        short8 bv = *(const short8*)(Wt + (size_t)(n0 + lrow) * Kd + k0 + lk);
        *(short8*)(Bs + lrow * 40 + lk) = bv;
        __syncthreads();
        short8 af[2], bf[2];
        for (int mi = 0; mi < 2; ++mi)
            af[mi] = *(short8*)(As + (wm*32 + mi*16 + r) * 40 + g*8);
        for (int ni = 0; ni < 2; ++ni)
            bf[ni] = *(short8*)(Bs + (wn*32 + ni*16 + r) * 40 + g*8);
        for (int mi = 0; mi < 2; ++mi)
            for (int ni = 0; ni < 2; ++ni)
                acc[mi][ni] = __builtin_amdgcn_mfma_f32_16x16x32_bf16(af[mi], bf[ni], acc[mi][ni], 0, 0, 0);
        __syncthreads();
    }

    for (int mi = 0; mi < 2; ++mi)
      for (int ni = 0; ni < 2; ++ni)
        for (int i = 0; i < 4; ++i) {
            int m = m0 + wm*32 + mi*16 + g*4 + i;
            int n = n0 + wn*32 + ni*16 + r;
            float v = acc[mi][ni][i] + bias[n];
            if (MODE == 0) {
                int b = m >> 11, t = m & 2047, h = n >> 6, hd = n & 63;
                ((short*)Out)[((((size_t)b*NH + h)*TT + t) << 6) + hd] = f2bf(v);
            } else if (MODE == 1) {
                int b = m >> 11, t = m & 2047, h = n >> 6, hd = n & 63;
                ((short*)Out)[(((size_t)b*NH + h)*HDim + hd)*SSZ + t] = f2bf(v);
            } else {
                ((float*)Out)[(size_t)m * DQq + n] = v;
            }
        }
}

// ---------------- FUSED attention v5: TBLK=32 (2 t-tiles/block) — each K/V
// fragment feeds 2 MFMAs, grid halves, per-barrier work doubles. Transposed
// QK^T (r14-verified), PV gather (r10-verified), C/D maps (r8-verified).
// V fragments preloaded before the barrier (r11 lesson: prefetch depth wins).
#define WPITCH 260   // f32 row pitch; 260 mod 32 == 4 (verified bank pattern)

__global__ __launch_bounds__(256) void attn_pv(
    const short* __restrict__ Q, const short* __restrict__ K,
    const short* __restrict__ Vt,
    const int* __restrict__ kpm, const float* __restrict__ amask,
    float* __restrict__ attnW, float* __restrict__ AO)
{
    __shared__ float s_wl[4][32];
    __shared__ float s_li[32];
    __shared__ float wch[32][WPITCH];

    int tid = threadIdx.x;
    int wave = tid >> 6, lane = tid & 63;
    int g = lane >> 4, r = lane & 15;
    int t0 = blockIdx.x * 32;
    int bh = blockIdx.y;
    int b = bh >> 3, h = bh & 7;

    const short* Qp = Q + ((size_t)bh * TT + t0) * HDim;
    const short* Kp = K + (size_t)bh * SSZ * HDim;

    short8 qa0 = *(const short8*)(Qp + r * HDim + g * 8);
    short8 qa1 = *(const short8*)(Qp + r * HDim + 32 + g * 8);
    short8 qb0 = *(const short8*)(Qp + (size_t)(16 + r) * HDim + g * 8);
    short8 qb1 = *(const short8*)(Qp + (size_t)(16 + r) * HDim + 32 + g * 8);

    const float* amrow_a = amask + (size_t)(t0 + r) * SSZ;
    const float* amrow_b = amask + (size_t)(t0 + 16 + r) * SSZ;
    const int*   kpmb  = kpm + b * SSZ;

    // ---- phase 1 (transposed, 2 t-tiles): denominators
    int ws0 = wave * 512;
    float lrun_a = 0.f, lrun_b = 0.f;
    for (int it = 0; it < 16; ++it) {
        int col0 = ws0 + it * 32;
        const short* kpA = Kp + (size_t)(col0 + r) * HDim;
        const short* kpB = Kp + (size_t)(col0 + 16 + r) * HDim;
        short8 kA0 = *(const short8*)(kpA + g * 8);
        short8 kA1 = *(const short8*)(kpA + 32 + g * 8);
        short8 kB0 = *(const short8*)(kpB + g * 8);
        short8 kB1 = *(const short8*)(kpB + 32 + g * 8);
        f32x4 sAa = (f32x4){0.f,0.f,0.f,0.f}, sBa = sAa, sAb = sAa, sBb = sAa;
        sAa = __builtin_amdgcn_mfma_f32_16x16x32_bf16(kA0, qa0, sAa, 0, 0, 0);
        sAa = __builtin_amdgcn_mfma_f32_16x16x32_bf16(kA1, qa1, sAa, 0, 0, 0);
        sBa = __builtin_amdgcn_mfma_f32_16x16x32_bf16(kB0, qa0, sBa, 0, 0, 0);
        sBa = __builtin_amdgcn_mfma_f32_16x16x32_bf16(kB1, qa1, sBa, 0, 0, 0);
        sAb = __builtin_amdgcn_mfma_f32_16x16x32_bf16(kA0, qb0, sAb, 0, 0, 0);
        sAb = __builtin_amdgcn_mfma_f32_16x16x32_bf16(kA1, qb1, sAb, 0, 0, 0);
        sBb = __builtin_amdgcn_mfma_f32_16x16x32_bf16(kB0, qb0, sBb, 0, 0, 0);
        sBb = __builtin_amdgcn_mfma_f32_16x16x32_bf16(kB1, qb1, sBb, 0, 0, 0);
        f32x4 amAa = *(const f32x4*)(amrow_a + col0 + g * 4);
        f32x4 amBa = *(const f32x4*)(amrow_a + col0 + 16 + g * 4);
        f32x4 amAb = *(const f32x4*)(amrow_b + col0 + g * 4);
        f32x4 amBb = *(const f32x4*)(amrow_b + col0 + 16 + g * 4);
        i32x4 okA = *(const i32x4*)(kpmb + col0 + g * 4);
        i32x4 okB = *(const i32x4*)(kpmb + col0 + 16 + g * 4);
        for (int i = 0; i < 4; ++i) {
            float vAa = sAa[i] * 0.125f + amAa[i]; if (okA[i] == 0) vAa = -1e30f;
            lrun_a += __expf(vAa);
            float vBa = sBa[i] * 0.125f + amBa[i]; if (okB[i] == 0) vBa = -1e30f;
            lrun_a += __expf(vBa);
            float vAb = sAb[i] * 0.125f + amAb[i]; if (okA[i] == 0) vAb = -1e30f;
            lrun_b += __expf(vAb);
            float vBb = sBb[i] * 0.125f + amBb[i]; if (okB[i] == 0) vBb = -1e30f;
            lrun_b += __expf(vBb);
        }
    }
    lrun_a += __shfl_xor(lrun_a, 16);
    lrun_a += __shfl_xor(lrun_a, 32);
    lrun_b += __shfl_xor(lrun_b, 16);
    lrun_b += __shfl_xor(lrun_b, 32);
    if (lane < 16) {
        s_wl[wave][lane] = lrun_a;
        s_wl[wave][16 + lane] = lrun_b;
    }
    __syncthreads();
    if (tid < 32)
        s_li[tid] = 1.0f / (s_wl[0][tid] + s_wl[1][tid] + s_wl[2][tid] + s_wl[3][tid]);
    __syncthreads();

    float li_a = s_li[r], li_b = s_li[16 + r];
    const short* vrow = Vt + ((size_t)bh * HDim + wave * 16 + r) * SSZ;
    float* wrow_a = attnW + ((size_t)bh * TT + t0 + r) * SSZ;
    float* wrow_b = attnW + ((size_t)bh * TT + t0 + 16 + r) * SSZ;
    f32x4 oacc_a = (f32x4){0.f, 0.f, 0.f, 0.f};
    f32x4 oacc_b = (f32x4){0.f, 0.f, 0.f, 0.f};

    // ---- phases 2+3 per 256-col chunk
    for (int ch = 0; ch < 8; ++ch) {
        // phase 2: wave computes its 64-col slice for both t-tiles
        for (int it = 0; it < 2; ++it) {
            int col0 = ch * 256 + wave * 64 + it * 32;
            const short* kpA = Kp + (size_t)(col0 + r) * HDim;
            const short* kpB = Kp + (size_t)(col0 + 16 + r) * HDim;
            short8 kA0 = *(const short8*)(kpA + g * 8);
            short8 kA1 = *(const short8*)(kpA + 32 + g * 8);
            short8 kB0 = *(const short8*)(kpB + g * 8);
            short8 kB1 = *(const short8*)(kpB + 32 + g * 8);
            f32x4 sAa = (f32x4){0.f,0.f,0.f,0.f}, sBa = sAa, sAb = sAa, sBb = sAa;
            sAa = __builtin_amdgcn_mfma_f32_16x16x32_bf16(kA0, qa0, sAa, 0, 0, 0);
            sAa = __builtin_amdgcn_mfma_f32_16x16x32_bf16(kA1, qa1, sAa, 0, 0, 0);
            sBa = __builtin_amdgcn_mfma_f32_16x16x32_bf16(kB0, qa0, sBa, 0, 0, 0);
            sBa = __builtin_amdgcn_mfma_f32_16x16x32_bf16(kB1, qa1, sBa, 0, 0, 0);
            sAb = __builtin_amdgcn_mfma_f32_16x16x32_bf16(kA0, qb0, sAb, 0, 0, 0);
            sAb = __builtin_amdgcn_mfma_f32_16x16x32_bf16(kA1, qb1, sAb, 0, 0, 0);
            sBb = __builtin_amdgcn_mfma_f32_16x16x32_bf16(kB0, qb0, sBb, 0, 0, 0);
            sBb = __builtin_amdgcn_mfma_f32_16x16x32_bf16(kB1, qb1, sBb, 0, 0, 0);
            f32x4 amAa = *(const f32x4*)(amrow_a + col0 + g * 4);
            f32x4 amBa = *(const f32x4*)(amrow_a + col0 + 16 + g * 4);
            f32x4 amAb = *(const f32x4*)(amrow_b + col0 + g * 4);
            f32x4 amBb = *(const f32x4*)(amrow_b + col0 + 16 + g * 4);
            i32x4 okA = *(const i32x4*)(kpmb + col0 + g * 4);
            i32x4 okB = *(const i32x4*)(kpmb + col0 + 16 + g * 4);
            f32x4 wAa, wBa, wAb, wBb;
            for (int i = 0; i < 4; ++i) {
                float vAa = sAa[i] * 0.125f + amAa[i]; if (okA[i] == 0) vAa = -1e30f;
                wAa[i] = __expf(vAa) * li_a;
                float vBa = sBa[i] * 0.125f + amBa[i]; if (okB[i] == 0) vBa = -1e30f;
                wBa[i] = __expf(vBa) * li_a;
                float vAb = sAb[i] * 0.125f + amAb[i]; if (okA[i] == 0) vAb = -1e30f;
                wAb[i] = __expf(vAb) * li_b;
                float vBb = sBb[i] * 0.125f + amBb[i]; if (okB[i] == 0) vBb = -1e30f;
                wBb[i] = __expf(vBb) * li_b;
            }
            *(f32x4*)(wrow_a + col0 + g * 4) = wAa;
            *(f32x4*)(wrow_a + col0 + 16 + g * 4) = wBa;
            *(f32x4*)(wrow_b + col0 + g * 4) = wAb;
            *(f32x4*)(wrow_b + col0 + 16 + g * 4) = wBb;
            int lcol = wave * 64 + it * 32;
            *(f32x4*)&wch[r][lcol + g * 4] = wAa;
            *(f32x4*)&wch[r][lcol + 16 + g * 4] = wBa;
            *(f32x4*)&wch[16 + r][lcol + g * 4] = wAb;
            *(f32x4*)&wch[16 + r][lcol + 16 + g * 4] = wBb;
        }
        // preload V for this chunk BEFORE the barrier (latency hides under it)
        short8 vf[8];
        #pragma unroll
        for (int s = 0; s < 8; ++s)
            vf[s] = *(const short8*)(vrow + ch * 256 + s * 32 + g * 8);

        __syncthreads();   // wch complete

        // phase 3: PV for both t-tiles, shared V fragments
        #pragma unroll
        for (int s = 0; s < 8; ++s) {
            const float* wpa = &wch[r][s * 32 + g * 8];
            const float* wpb = &wch[16 + r][s * 32 + g * 8];
            f32x4 a0 = *(const f32x4*)wpa, a1 = *(const f32x4*)(wpa + 4);
            f32x4 b0 = *(const f32x4*)wpb, b1 = *(const f32x4*)(wpb + 4);
            short8 wfa, wfb;
            wfa[0]=f2bf(a0[0]); wfa[1]=f2bf(a0[1]); wfa[2]=f2bf(a0[2]); wfa[3]=f2bf(a0[3]);
            wfa[4]=f2bf(a1[0]); wfa[5]=f2bf(a1[1]); wfa[6]=f2bf(a1[2]); wfa[7]=f2bf(a1[3]);
            wfb[0]=f2bf(b0[0]); wfb[1]=f2bf(b0[1]); wfb[2]=f2bf(b0[2]); wfb[3]=f2bf(b0[3]);
            wfb[4]=f2bf(b1[0]); wfb[5]=f2bf(b1[1]); wfb[6]=f2bf(b1[2]); wfb[7]=f2bf(b1[3]);
            oacc_a = __builtin_amdgcn_mfma_f32_16x16x32_bf16(wfa, vf[s], oacc_a, 0, 0, 0);
            oacc_b = __builtin_amdgcn_mfma_f32_16x16x32_bf16(wfb, vf[s], oacc_b, 0, 0, 0);
        }
        __syncthreads();   // wch reads done before next chunk overwrites
    }

    // C/D (verified r8): oacc[i] = PV[t-local = g*4+i][hd-local = r]
    for (int i = 0; i < 4; ++i) {
        AO[((size_t)(b * TT + t0 + g*4 + i)) * DQq + h * HDim + wave * 16 + r] = oacc_a[i];
        AO[((size_t)(b * TT + t0 + 16 + g*4 + i)) * DQq + h * HDim + wave * 16 + r] = oacc_b[i];
    }
}

extern "C" void kernel_launch(void* const* d_in, const int* in_sizes, int n_in,
                              void* d_out, int out_size, void* d_ws, size_t ws_size,
                              hipStream_t stream)
{
    const float* query = (const float*)d_in[0];
    const float* key   = (const float*)d_in[1];
    const float* value = (const float*)d_in[2];
    const int*   kpm   = (const int*)d_in[3];
    const float* amask = (const float*)d_in[4];
    const float* Wq = (const float*)d_in[5];
    const float* bq = (const float*)d_in[6];
    const float* Wk = (const float*)d_in[7];
    const float* bk = (const float*)d_in[8];
    const float* Wv = (const float*)d_in[9];
    const float* bv = (const float*)d_in[10];
    const float* Wo = (const float*)d_in[11];
    const float* bo = (const float*)d_in[12];

    char* ws = (char*)d_ws;
    short* WqT = (short*)ws;  ws += (size_t)512 * 512 * 2;
    short* WkT = (short*)ws;  ws += (size_t)512 * 1024 * 2;
    short* WvT = (short*)ws;  ws += (size_t)512 * 1024 * 2;
    short* WoT = (short*)ws;  ws += (size_t)512 * 512 * 2;
    short* Qh  = (short*)ws;  ws += (size_t)BB * NH * TT * HDim * 2;
    short* Kh  = (short*)ws;  ws += (size_t)BB * NH * SSZ * HDim * 2;
    short* Vth = (short*)ws;  ws += (size_t)BB * NH * HDim * SSZ * 2;
    float* AOf = (float*)ws;  ws += (size_t)BB * TT * DQq * 4;

    float* out0  = (float*)d_out;
    float* attnW = out0 + (size_t)BB * TT * DQq;

    wt_kernel<<<(512*512)/256, 256, 0, stream>>>(Wq, WqT, 512);
    wt_kernel<<<(1024*512)/256, 256, 0, stream>>>(Wk, WkT, 1024);
    wt_kernel<<<(1024*512)/256, 256, 0, stream>>>(Wv, WvT, 1024);
    wt_kernel<<<(512*512)/256, 256, 0, stream>>>(Wo, WoT, 512);

    dim3 gp(8192 / 64, 512 / 64);
    gemm_proj<0, false><<<gp, 256, 0, stream>>>(query, WqT, bq, Qh, 512);
    gemm_proj<0, false><<<gp, 256, 0, stream>>>(key,   WkT, bk, Kh, 1024);
    gemm_proj<1, false><<<gp, 256, 0, stream>>>(value, WvT, bv, Vth, 1024);

    dim3 ga(TT / 32, BB * NH);
    attn_pv<<<ga, 256, 0, stream>>>(Qh, Kh, Vth, kpm, amask, attnW, AOf);

    gemm_proj<2, false><<<gp, 256, 0, stream>>>(AOf, WoT, bo, out0, 512);
}

// Round 17
// 465.809 us; speedup vs baseline: 1.5191x; 1.0084x over previous
//
#include <hip/hip_runtime.h>
#include <hip/hip_bf16.h>

#define BB 4
#define TT 2048
#define SSZ 2048
#define DQq 512
#define NH 8
#define HDim 64

typedef __attribute__((ext_vector_type(8))) short short8;
typedef __attribute__((ext_vector_type(4))) short bf16x4;
typedef __attribute__((ext_vector_type(4))) float f32x4;
typedef __attribute__((ext_vector_type(4))) int i32x4;

__device__ __forceinline__ short f2bf(float f) {
    union { float f; unsigned u; } v; v.f = f;
    unsigned r = v.u + 0x7fffu + ((v.u >> 16) & 1u);
    return (short)(r >> 16);
}

// ---------------- weight transpose + bf16 convert: W[Kd][512] -> Wt[512][Kd]
// (verified round 5)
__global__ void wt_kernel(const float* __restrict__ W, short* __restrict__ Wt, int Kd) {
    int tid = blockIdx.x * 256 + threadIdx.x;
    int n = tid / Kd, k = tid - n * Kd;
    Wt[tid] = f2bf(W[(size_t)k * DQq + n]);
}

// ---------------- projection GEMM (verified round 5, unchanged)
template<int MODE, bool IN_BF16>
__global__ __launch_bounds__(256) void gemm_proj(
    const void* __restrict__ Xv, const short* __restrict__ Wt,
    const float* __restrict__ bias, void* __restrict__ Out, int Kd)
{
    __shared__ short As[64 * 40];
    __shared__ short Bs[64 * 40];
    int tid = threadIdx.x;
    int wave = tid >> 6, lane = tid & 63;
    int g = lane >> 4, r = lane & 15;
    int wm = wave >> 1, wn = wave & 1;
    int m0 = blockIdx.x * 64, n0 = blockIdx.y * 64;

    const float* Xf = (const float*)Xv;
    const short* Xb = (const short*)Xv;

    f32x4 acc[2][2];
    for (int a = 0; a < 2; ++a) for (int b2 = 0; b2 < 2; ++b2) acc[a][b2] = (f32x4){0.f,0.f,0.f,0.f};

    int lrow = tid >> 2, lk = (tid & 3) * 8;

    for (int k0 = 0; k0 < Kd; k0 += 32) {
        short8 av;
        if (IN_BF16) {
            av = *(const short8*)(Xb + (size_t)(m0 + lrow) * Kd + k0 + lk);
        } else {
            const f32x4* p = (const f32x4*)(Xf + (size_t)(m0 + lrow) * Kd + k0 + lk);
            f32x4 x0 = p[0], x1 = p[1];
            av[0]=f2bf(x0[0]); av[1]=f2bf(x0[1]); av[2]=f2bf(x0[2]); av[3]=f2bf(x0[3]);
            av[4]=f2bf(x1[0]); av[5]=f2bf(x1[1]); av[6]=f2bf(x1[2]); av[7]=f2bf(x1[3]);
        }
        *(short8*)(As + lrow * 40 + lk) = av;
        short8 bv = *(const short8*)(Wt + (size_t)(n0 + lrow) * Kd + k0 + lk);
        *(short8*)(Bs + lrow * 40 + lk) = bv;
        __syncthreads();
        short8 af[2], bf[2];
        for (int mi = 0; mi < 2; ++mi)
            af[mi] = *(short8*)(As + (wm*32 + mi*16 + r) * 40 + g*8);
        for (int ni = 0; ni < 2; ++ni)
            bf[ni] = *(short8*)(Bs + (wn*32 + ni*16 + r) * 40 + g*8);
        for (int mi = 0; mi < 2; ++mi)
            for (int ni = 0; ni < 2; ++ni)
                acc[mi][ni] = __builtin_amdgcn_mfma_f32_16x16x32_bf16(af[mi], bf[ni], acc[mi][ni], 0, 0, 0);
        __syncthreads();
    }

    for (int mi = 0; mi < 2; ++mi)
      for (int ni = 0; ni < 2; ++ni)
        for (int i = 0; i < 4; ++i) {
            int m = m0 + wm*32 + mi*16 + g*4 + i;
            int n = n0 + wn*32 + ni*16 + r;
            float v = acc[mi][ni][i] + bias[n];
            if (MODE == 0) {
                int b = m >> 11, t = m & 2047, h = n >> 6, hd = n & 63;
                ((short*)Out)[((((size_t)b*NH + h)*TT + t) << 6) + hd] = f2bf(v);
            } else if (MODE == 1) {
                int b = m >> 11, t = m & 2047, h = n >> 6, hd = n & 63;
                ((short*)Out)[(((size_t)b*NH + h)*HDim + hd)*SSZ + t] = f2bf(v);
            } else {
                ((float*)Out)[(size_t)m * DQq + n] = v;
            }
        }
}

// ---------------- FUSED attention v6: wch stored as bf16 (f2bf moved to
// phase 2) -> LDS 34->17 KB -> 8 blocks/CU. Phase 3 = pure ds_read+MFMA.
// bf16 values / MFMA inputs / accumulation order identical to r15 -> output
// bit-identical. Transposed QK^T (r14), PV gather (r10), C/D maps (r8).
#define WPITCH 264   // bf16 row pitch; 528 B rows: 16B-aligned, 2-way banks

__global__ __launch_bounds__(256) void attn_pv(
    const short* __restrict__ Q, const short* __restrict__ K,
    const short* __restrict__ Vt,
    const int* __restrict__ kpm, const float* __restrict__ amask,
    float* __restrict__ attnW, float* __restrict__ AO)
{
    __shared__ float s_wl[4][32];
    __shared__ float s_li[32];
    __shared__ short wch[32][WPITCH];

    int tid = threadIdx.x;
    int wave = tid >> 6, lane = tid & 63;
    int g = lane >> 4, r = lane & 15;
    int t0 = blockIdx.x * 32;
    int bh = blockIdx.y;
    int b = bh >> 3, h = bh & 7;

    const short* Qp = Q + ((size_t)bh * TT + t0) * HDim;
    const short* Kp = K + (size_t)bh * SSZ * HDim;

    short8 qa0 = *(const short8*)(Qp + r * HDim + g * 8);
    short8 qa1 = *(const short8*)(Qp + r * HDim + 32 + g * 8);
    short8 qb0 = *(const short8*)(Qp + (size_t)(16 + r) * HDim + g * 8);
    short8 qb1 = *(const short8*)(Qp + (size_t)(16 + r) * HDim + 32 + g * 8);

    const float* amrow_a = amask + (size_t)(t0 + r) * SSZ;
    const float* amrow_b = amask + (size_t)(t0 + 16 + r) * SSZ;
    const int*   kpmb  = kpm + b * SSZ;

    // ---- phase 1 (transposed, 2 t-tiles): denominators (r15-verified)
    int ws0 = wave * 512;
    float lrun_a = 0.f, lrun_b = 0.f;
    for (int it = 0; it < 16; ++it) {
        int col0 = ws0 + it * 32;
        const short* kpA = Kp + (size_t)(col0 + r) * HDim;
        const short* kpB = Kp + (size_t)(col0 + 16 + r) * HDim;
        short8 kA0 = *(const short8*)(kpA + g * 8);
        short8 kA1 = *(const short8*)(kpA + 32 + g * 8);
        short8 kB0 = *(const short8*)(kpB + g * 8);
        short8 kB1 = *(const short8*)(kpB + 32 + g * 8);
        f32x4 sAa = (f32x4){0.f,0.f,0.f,0.f}, sBa = sAa, sAb = sAa, sBb = sAa;
        sAa = __builtin_amdgcn_mfma_f32_16x16x32_bf16(kA0, qa0, sAa, 0, 0, 0);
        sAa = __builtin_amdgcn_mfma_f32_16x16x32_bf16(kA1, qa1, sAa, 0, 0, 0);
        sBa = __builtin_amdgcn_mfma_f32_16x16x32_bf16(kB0, qa0, sBa, 0, 0, 0);
        sBa = __builtin_amdgcn_mfma_f32_16x16x32_bf16(kB1, qa1, sBa, 0, 0, 0);
        sAb = __builtin_amdgcn_mfma_f32_16x16x32_bf16(kA0, qb0, sAb, 0, 0, 0);
        sAb = __builtin_amdgcn_mfma_f32_16x16x32_bf16(kA1, qb1, sAb, 0, 0, 0);
        sBb = __builtin_amdgcn_mfma_f32_16x16x32_bf16(kB0, qb0, sBb, 0, 0, 0);
        sBb = __builtin_amdgcn_mfma_f32_16x16x32_bf16(kB1, qb1, sBb, 0, 0, 0);
        f32x4 amAa = *(const f32x4*)(amrow_a + col0 + g * 4);
        f32x4 amBa = *(const f32x4*)(amrow_a + col0 + 16 + g * 4);
        f32x4 amAb = *(const f32x4*)(amrow_b + col0 + g * 4);
        f32x4 amBb = *(const f32x4*)(amrow_b + col0 + 16 + g * 4);
        i32x4 okA = *(const i32x4*)(kpmb + col0 + g * 4);
        i32x4 okB = *(const i32x4*)(kpmb + col0 + 16 + g * 4);
        for (int i = 0; i < 4; ++i) {
            float vAa = sAa[i] * 0.125f + amAa[i]; if (okA[i] == 0) vAa = -1e30f;
            lrun_a += __expf(vAa);
            float vBa = sBa[i] * 0.125f + amBa[i]; if (okB[i] == 0) vBa = -1e30f;
            lrun_a += __expf(vBa);
            float vAb = sAb[i] * 0.125f + amAb[i]; if (okA[i] == 0) vAb = -1e30f;
            lrun_b += __expf(vAb);
            float vBb = sBb[i] * 0.125f + amBb[i]; if (okB[i] == 0) vBb = -1e30f;
            lrun_b += __expf(vBb);
        }
    }
    lrun_a += __shfl_xor(lrun_a, 16);
    lrun_a += __shfl_xor(lrun_a, 32);
    lrun_b += __shfl_xor(lrun_b, 16);
    lrun_b += __shfl_xor(lrun_b, 32);
    if (lane < 16) {
        s_wl[wave][lane] = lrun_a;
        s_wl[wave][16 + lane] = lrun_b;
    }
    __syncthreads();
    if (tid < 32)
        s_li[tid] = 1.0f / (s_wl[0][tid] + s_wl[1][tid] + s_wl[2][tid] + s_wl[3][tid]);
    __syncthreads();

    float li_a = s_li[r], li_b = s_li[16 + r];
    const short* vrow = Vt + ((size_t)bh * HDim + wave * 16 + r) * SSZ;
    float* wrow_a = attnW + ((size_t)bh * TT + t0 + r) * SSZ;
    float* wrow_b = attnW + ((size_t)bh * TT + t0 + 16 + r) * SSZ;
    f32x4 oacc_a = (f32x4){0.f, 0.f, 0.f, 0.f};
    f32x4 oacc_b = (f32x4){0.f, 0.f, 0.f, 0.f};

    // ---- phases 2+3 per 256-col chunk
    for (int ch = 0; ch < 8; ++ch) {
        // phase 2: wave computes its 64-col slice for both t-tiles;
        // f32 -> global attnW, bf16 -> LDS wch
        for (int it = 0; it < 2; ++it) {
            int col0 = ch * 256 + wave * 64 + it * 32;
            const short* kpA = Kp + (size_t)(col0 + r) * HDim;
            const short* kpB = Kp + (size_t)(col0 + 16 + r) * HDim;
            short8 kA0 = *(const short8*)(kpA + g * 8);
            short8 kA1 = *(const short8*)(kpA + 32 + g * 8);
            short8 kB0 = *(const short8*)(kpB + g * 8);
            short8 kB1 = *(const short8*)(kpB + 32 + g * 8);
            f32x4 sAa = (f32x4){0.f,0.f,0.f,0.f}, sBa = sAa, sAb = sAa, sBb = sAa;
            sAa = __builtin_amdgcn_mfma_f32_16x16x32_bf16(kA0, qa0, sAa, 0, 0, 0);
            sAa = __builtin_amdgcn_mfma_f32_16x16x32_bf16(kA1, qa1, sAa, 0, 0, 0);
            sBa = __builtin_amdgcn_mfma_f32_16x16x32_bf16(kB0, qa0, sBa, 0, 0, 0);
            sBa = __builtin_amdgcn_mfma_f32_16x16x32_bf16(kB1, qa1, sBa, 0, 0, 0);
            sAb = __builtin_amdgcn_mfma_f32_16x16x32_bf16(kA0, qb0, sAb, 0, 0, 0);
            sAb = __builtin_amdgcn_mfma_f32_16x16x32_bf16(kA1, qb1, sAb, 0, 0, 0);
            sBb = __builtin_amdgcn_mfma_f32_16x16x32_bf16(kB0, qb0, sBb, 0, 0, 0);
            sBb = __builtin_amdgcn_mfma_f32_16x16x32_bf16(kB1, qb1, sBb, 0, 0, 0);
            f32x4 amAa = *(const f32x4*)(amrow_a + col0 + g * 4);
            f32x4 amBa = *(const f32x4*)(amrow_a + col0 + 16 + g * 4);
            f32x4 amAb = *(const f32x4*)(amrow_b + col0 + g * 4);
            f32x4 amBb = *(const f32x4*)(amrow_b + col0 + 16 + g * 4);
            i32x4 okA = *(const i32x4*)(kpmb + col0 + g * 4);
            i32x4 okB = *(const i32x4*)(kpmb + col0 + 16 + g * 4);
            f32x4 wAa, wBa, wAb, wBb;
            bf16x4 pAa, pBa, pAb, pBb;
            for (int i = 0; i < 4; ++i) {
                float vAa = sAa[i] * 0.125f + amAa[i]; if (okA[i] == 0) vAa = -1e30f;
                wAa[i] = __expf(vAa) * li_a; pAa[i] = f2bf(wAa[i]);
                float vBa = sBa[i] * 0.125f + amBa[i]; if (okB[i] == 0) vBa = -1e30f;
                wBa[i] = __expf(vBa) * li_a; pBa[i] = f2bf(wBa[i]);
                float vAb = sAb[i] * 0.125f + amAb[i]; if (okA[i] == 0) vAb = -1e30f;
                wAb[i] = __expf(vAb) * li_b; pAb[i] = f2bf(wAb[i]);
                float vBb = sBb[i] * 0.125f + amBb[i]; if (okB[i] == 0) vBb = -1e30f;
                wBb[i] = __expf(vBb) * li_b; pBb[i] = f2bf(wBb[i]);
            }
            *(f32x4*)(wrow_a + col0 + g * 4) = wAa;
            *(f32x4*)(wrow_a + col0 + 16 + g * 4) = wBa;
            *(f32x4*)(wrow_b + col0 + g * 4) = wAb;
            *(f32x4*)(wrow_b + col0 + 16 + g * 4) = wBb;
            int lcol = wave * 64 + it * 32;
            *(bf16x4*)&wch[r][lcol + g * 4] = pAa;
            *(bf16x4*)&wch[r][lcol + 16 + g * 4] = pBa;
            *(bf16x4*)&wch[16 + r][lcol + g * 4] = pAb;
            *(bf16x4*)&wch[16 + r][lcol + 16 + g * 4] = pBb;
        }
        // preload V for this chunk BEFORE the barrier (latency hides under it)
        short8 vf[8];
        #pragma unroll
        for (int s = 0; s < 8; ++s)
            vf[s] = *(const short8*)(vrow + ch * 256 + s * 32 + g * 8);

        __syncthreads();   // wch complete

        // phase 3: pure ds_read_b128 + MFMA, both t-tiles share V fragments
        #pragma unroll
        for (int s = 0; s < 8; ++s) {
            short8 wfa = *(const short8*)&wch[r][s * 32 + g * 8];
            short8 wfb = *(const short8*)&wch[16 + r][s * 32 + g * 8];
            oacc_a = __builtin_amdgcn_mfma_f32_16x16x32_bf16(wfa, vf[s], oacc_a, 0, 0, 0);
            oacc_b = __builtin_amdgcn_mfma_f32_16x16x32_bf16(wfb, vf[s], oacc_b, 0, 0, 0);
        }
        __syncthreads();   // wch reads done before next chunk overwrites
    }

    // C/D (verified r8): oacc[i] = PV[t-local = g*4+i][hd-local = r]
    for (int i = 0; i < 4; ++i) {
        AO[((size_t)(b * TT + t0 + g*4 + i)) * DQq + h * HDim + wave * 16 + r] = oacc_a[i];
        AO[((size_t)(b * TT + t0 + 16 + g*4 + i)) * DQq + h * HDim + wave * 16 + r] = oacc_b[i];
    }
}

extern "C" void kernel_launch(void* const* d_in, const int* in_sizes, int n_in,
                              void* d_out, int out_size, void* d_ws, size_t ws_size,
                              hipStream_t stream)
{
    const float* query = (const float*)d_in[0];
    const float* key   = (const float*)d_in[1];
    const float* value = (const float*)d_in[2];
    const int*   kpm   = (const int*)d_in[3];
    const float* amask = (const float*)d_in[4];
    const float* Wq = (const float*)d_in[5];
    const float* bq = (const float*)d_in[6];
    const float* Wk = (const float*)d_in[7];
    const float* bk = (const float*)d_in[8];
    const float* Wv = (const float*)d_in[9];
    const float* bv = (const float*)d_in[10];
    const float* Wo = (const float*)d_in[11];
    const float* bo = (const float*)d_in[12];

    char* ws = (char*)d_ws;
    short* WqT = (short*)ws;  ws += (size_t)512 * 512 * 2;
    short* WkT = (short*)ws;  ws += (size_t)512 * 1024 * 2;
    short* WvT = (short*)ws;  ws += (size_t)512 * 1024 * 2;
    short* WoT = (short*)ws;  ws += (size_t)512 * 512 * 2;
    short* Qh  = (short*)ws;  ws += (size_t)BB * NH * TT * HDim * 2;
    short* Kh  = (short*)ws;  ws += (size_t)BB * NH * SSZ * HDim * 2;
    short* Vth = (short*)ws;  ws += (size_t)BB * NH * HDim * SSZ * 2;
    float* AOf = (float*)ws;  ws += (size_t)BB * TT * DQq * 4;

    float* out0  = (float*)d_out;
    float* attnW = out0 + (size_t)BB * TT * DQq;

    wt_kernel<<<(512*512)/256, 256, 0, stream>>>(Wq, WqT, 512);
    wt_kernel<<<(1024*512)/256, 256, 0, stream>>>(Wk, WkT, 1024);
    wt_kernel<<<(1024*512)/256, 256, 0, stream>>>(Wv, WvT, 1024);
    wt_kernel<<<(512*512)/256, 256, 0, stream>>>(Wo, WoT, 512);

    dim3 gp(8192 / 64, 512 / 64);
    gemm_proj<0, false><<<gp, 256, 0, stream>>>(query, WqT, bq, Qh, 512);
    gemm_proj<0, false><<<gp, 256, 0, stream>>>(key,   WkT, bk, Kh, 1024);
    gemm_proj<1, false><<<gp, 256, 0, stream>>>(value, WvT, bv, Vth, 1024);

    dim3 ga(TT / 32, BB * NH);
    attn_pv<<<ga, 256, 0, stream>>>(Qh, Kh, Vth, kpm, amask, attnW, AOf);

    gemm_proj<2, false><<<gp, 256, 0, stream>>>(AOf, WoT, bo, out0, 512);
}

// Round 18
// 419.209 us; speedup vs baseline: 1.6879x; 1.1112x over previous
//
#include <hip/hip_runtime.h>
#include <hip/hip_bf16.h>

#define BB 4
#define TT 2048
#define SSZ 2048
#define DQq 512
#define NH 8
#define HDim 64

typedef __attribute__((ext_vector_type(8))) short short8;
typedef __attribute__((ext_vector_type(4))) short bf16x4;
typedef __attribute__((ext_vector_type(4))) float f32x4;
typedef __attribute__((ext_vector_type(4))) int i32x4;

__device__ __forceinline__ short f2bf(float f) {
    union { float f; unsigned u; } v; v.f = f;
    unsigned r = v.u + 0x7fffu + ((v.u >> 16) & 1u);
    return (short)(r >> 16);
}

// ---------------- weight transpose + bf16 convert: W[Kd][512] -> Wt[512][Kd]
// (verified round 5)
__global__ void wt_kernel(const float* __restrict__ W, short* __restrict__ Wt, int Kd) {
    int tid = blockIdx.x * 256 + threadIdx.x;
    int n = tid / Kd, k = tid - n * Kd;
    Wt[tid] = f2bf(W[(size_t)k * DQq + n]);
}

// ---------------- projection GEMM (verified round 5, unchanged)
template<int MODE, bool IN_BF16>
__global__ __launch_bounds__(256) void gemm_proj(
    const void* __restrict__ Xv, const short* __restrict__ Wt,
    const float* __restrict__ bias, void* __restrict__ Out, int Kd)
{
    __shared__ short As[64 * 40];
    __shared__ short Bs[64 * 40];
    int tid = threadIdx.x;
    int wave = tid >> 6, lane = tid & 63;
    int g = lane >> 4, r = lane & 15;
    int wm = wave >> 1, wn = wave & 1;
    int m0 = blockIdx.x * 64, n0 = blockIdx.y * 64;

    const float* Xf = (const float*)Xv;
    const short* Xb = (const short*)Xv;

    f32x4 acc[2][2];
    for (int a = 0; a < 2; ++a) for (int b2 = 0; b2 < 2; ++b2) acc[a][b2] = (f32x4){0.f,0.f,0.f,0.f};

    int lrow = tid >> 2, lk = (tid & 3) * 8;

    for (int k0 = 0; k0 < Kd; k0 += 32) {
        short8 av;
        if (IN_BF16) {
            av = *(const short8*)(Xb + (size_t)(m0 + lrow) * Kd + k0 + lk);
        } else {
            const f32x4* p = (const f32x4*)(Xf + (size_t)(m0 + lrow) * Kd + k0 + lk);
            f32x4 x0 = p[0], x1 = p[1];
            av[0]=f2bf(x0[0]); av[1]=f2bf(x0[1]); av[2]=f2bf(x0[2]); av[3]=f2bf(x0[3]);
            av[4]=f2bf(x1[0]); av[5]=f2bf(x1[1]); av[6]=f2bf(x1[2]); av[7]=f2bf(x1[3]);
        }
        *(short8*)(As + lrow * 40 + lk) = av;
        short8 bv = *(const short8*)(Wt + (size_t)(n0 + lrow) * Kd + k0 + lk);
        *(short8*)(Bs + lrow * 40 + lk) = bv;
        __syncthreads();
        short8 af[2], bf[2];
        for (int mi = 0; mi < 2; ++mi)
            af[mi] = *(short8*)(As + (wm*32 + mi*16 + r) * 40 + g*8);
        for (int ni = 0; ni < 2; ++ni)
            bf[ni] = *(short8*)(Bs + (wn*32 + ni*16 + r) * 40 + g*8);
        for (int mi = 0; mi < 2; ++mi)
            for (int ni = 0; ni < 2; ++ni)
                acc[mi][ni] = __builtin_amdgcn_mfma_f32_16x16x32_bf16(af[mi], bf[ni], acc[mi][ni], 0, 0, 0);
        __syncthreads();
    }

    for (int mi = 0; mi < 2; ++mi)
      for (int ni = 0; ni < 2; ++ni)
        for (int i = 0; i < 4; ++i) {
            int m = m0 + wm*32 + mi*16 + g*4 + i;
            int n = n0 + wn*32 + ni*16 + r;
            float v = acc[mi][ni][i] + bias[n];
            if (MODE == 0) {
                int b = m >> 11, t = m & 2047, h = n >> 6, hd = n & 63;
                ((short*)Out)[((((size_t)b*NH + h)*TT + t) << 6) + hd] = f2bf(v);
            } else if (MODE == 1) {
                int b = m >> 11, t = m & 2047, h = n >> 6, hd = n & 63;
                ((short*)Out)[(((size_t)b*NH + h)*HDim + hd)*SSZ + t] = f2bf(v);
            } else {
                ((float*)Out)[(size_t)m * DQq + n] = v;
            }
        }
}

// ---------------- FUSED attention v7: TBLK=64 (4 t-tiles/block). Each K/V
// fragment feeds 4 MFMAs; block count halves -> K/amask traffic halves.
// Transposed QK^T (r14/r15), PV gather (r10), C/D maps (r8), bf16 wch (r17).
#define WPITCH 264   // bf16 row pitch; 528 B rows: 16B-aligned, 2-way banks

__global__ __launch_bounds__(256) void attn_pv(
    const short* __restrict__ Q, const short* __restrict__ K,
    const short* __restrict__ Vt,
    const int* __restrict__ kpm, const float* __restrict__ amask,
    float* __restrict__ attnW, float* __restrict__ AO)
{
    __shared__ float s_wl[4][64];
    __shared__ float s_li[64];
    __shared__ short wch[64][WPITCH];

    int tid = threadIdx.x;
    int wave = tid >> 6, lane = tid & 63;
    int g = lane >> 4, r = lane & 15;
    int t0 = blockIdx.x * 64;
    int bh = blockIdx.y;
    int b = bh >> 3, h = bh & 7;

    const short* Qp = Q + ((size_t)bh * TT + t0) * HDim;
    const short* Kp = K + (size_t)bh * SSZ * HDim;

    short8 qf[4][2];
    #pragma unroll
    for (int tt = 0; tt < 4; ++tt) {
        qf[tt][0] = *(const short8*)(Qp + (size_t)(tt * 16 + r) * HDim + g * 8);
        qf[tt][1] = *(const short8*)(Qp + (size_t)(tt * 16 + r) * HDim + 32 + g * 8);
    }

    const float* amrow[4];
    #pragma unroll
    for (int tt = 0; tt < 4; ++tt)
        amrow[tt] = amask + (size_t)(t0 + tt * 16 + r) * SSZ;
    const int* kpmb = kpm + b * SSZ;

    // ---- phase 1 (transposed, 4 t-tiles): denominators
    int ws0 = wave * 512;
    float lrun[4] = {0.f, 0.f, 0.f, 0.f};
    for (int it = 0; it < 16; ++it) {
        int col0 = ws0 + it * 32;
        const short* kpA = Kp + (size_t)(col0 + r) * HDim;
        const short* kpB = Kp + (size_t)(col0 + 16 + r) * HDim;
        short8 kA0 = *(const short8*)(kpA + g * 8);
        short8 kA1 = *(const short8*)(kpA + 32 + g * 8);
        short8 kB0 = *(const short8*)(kpB + g * 8);
        short8 kB1 = *(const short8*)(kpB + 32 + g * 8);
        i32x4 okA = *(const i32x4*)(kpmb + col0 + g * 4);
        i32x4 okB = *(const i32x4*)(kpmb + col0 + 16 + g * 4);
        #pragma unroll
        for (int tt = 0; tt < 4; ++tt) {
            f32x4 sA = (f32x4){0.f,0.f,0.f,0.f}, sB = (f32x4){0.f,0.f,0.f,0.f};
            sA = __builtin_amdgcn_mfma_f32_16x16x32_bf16(kA0, qf[tt][0], sA, 0, 0, 0);
            sA = __builtin_amdgcn_mfma_f32_16x16x32_bf16(kA1, qf[tt][1], sA, 0, 0, 0);
            sB = __builtin_amdgcn_mfma_f32_16x16x32_bf16(kB0, qf[tt][0], sB, 0, 0, 0);
            sB = __builtin_amdgcn_mfma_f32_16x16x32_bf16(kB1, qf[tt][1], sB, 0, 0, 0);
            f32x4 amA = *(const f32x4*)(amrow[tt] + col0 + g * 4);
            f32x4 amB = *(const f32x4*)(amrow[tt] + col0 + 16 + g * 4);
            for (int i = 0; i < 4; ++i) {
                float vA = sA[i] * 0.125f + amA[i]; if (okA[i] == 0) vA = -1e30f;
                lrun[tt] += __expf(vA);
                float vB = sB[i] * 0.125f + amB[i]; if (okB[i] == 0) vB = -1e30f;
                lrun[tt] += __expf(vB);
            }
        }
    }
    #pragma unroll
    for (int tt = 0; tt < 4; ++tt) {
        lrun[tt] += __shfl_xor(lrun[tt], 16);
        lrun[tt] += __shfl_xor(lrun[tt], 32);
    }
    if (lane < 16) {
        #pragma unroll
        for (int tt = 0; tt < 4; ++tt)
            s_wl[wave][tt * 16 + lane] = lrun[tt];
    }
    __syncthreads();
    if (tid < 64)
        s_li[tid] = 1.0f / (s_wl[0][tid] + s_wl[1][tid] + s_wl[2][tid] + s_wl[3][tid]);
    __syncthreads();

    float li[4];
    float* wrow[4];
    #pragma unroll
    for (int tt = 0; tt < 4; ++tt) {
        li[tt] = s_li[tt * 16 + r];
        wrow[tt] = attnW + ((size_t)bh * TT + t0 + tt * 16 + r) * SSZ;
    }
    const short* vrow = Vt + ((size_t)bh * HDim + wave * 16 + r) * SSZ;
    f32x4 oacc[4];
    #pragma unroll
    for (int tt = 0; tt < 4; ++tt) oacc[tt] = (f32x4){0.f, 0.f, 0.f, 0.f};

    // ---- phases 2+3 per 256-col chunk
    for (int ch = 0; ch < 8; ++ch) {
        // phase 2: wave's 64-col slice for all 4 t-tiles
        for (int it = 0; it < 2; ++it) {
            int col0 = ch * 256 + wave * 64 + it * 32;
            const short* kpA = Kp + (size_t)(col0 + r) * HDim;
            const short* kpB = Kp + (size_t)(col0 + 16 + r) * HDim;
            short8 kA0 = *(const short8*)(kpA + g * 8);
            short8 kA1 = *(const short8*)(kpA + 32 + g * 8);
            short8 kB0 = *(const short8*)(kpB + g * 8);
            short8 kB1 = *(const short8*)(kpB + 32 + g * 8);
            i32x4 okA = *(const i32x4*)(kpmb + col0 + g * 4);
            i32x4 okB = *(const i32x4*)(kpmb + col0 + 16 + g * 4);
            int lcol = wave * 64 + it * 32;
            #pragma unroll
            for (int tt = 0; tt < 4; ++tt) {
                f32x4 sA = (f32x4){0.f,0.f,0.f,0.f}, sB = (f32x4){0.f,0.f,0.f,0.f};
                sA = __builtin_amdgcn_mfma_f32_16x16x32_bf16(kA0, qf[tt][0], sA, 0, 0, 0);
                sA = __builtin_amdgcn_mfma_f32_16x16x32_bf16(kA1, qf[tt][1], sA, 0, 0, 0);
                sB = __builtin_amdgcn_mfma_f32_16x16x32_bf16(kB0, qf[tt][0], sB, 0, 0, 0);
                sB = __builtin_amdgcn_mfma_f32_16x16x32_bf16(kB1, qf[tt][1], sB, 0, 0, 0);
                f32x4 amA = *(const f32x4*)(amrow[tt] + col0 + g * 4);
                f32x4 amB = *(const f32x4*)(amrow[tt] + col0 + 16 + g * 4);
                f32x4 wA, wB;
                bf16x4 pA, pB;
                for (int i = 0; i < 4; ++i) {
                    float vA = sA[i] * 0.125f + amA[i]; if (okA[i] == 0) vA = -1e30f;
                    wA[i] = __expf(vA) * li[tt]; pA[i] = f2bf(wA[i]);
                    float vB = sB[i] * 0.125f + amB[i]; if (okB[i] == 0) vB = -1e30f;
                    wB[i] = __expf(vB) * li[tt]; pB[i] = f2bf(wB[i]);
                }
                *(f32x4*)(wrow[tt] + col0 + g * 4) = wA;
                *(f32x4*)(wrow[tt] + col0 + 16 + g * 4) = wB;
                *(bf16x4*)&wch[tt * 16 + r][lcol + g * 4] = pA;
                *(bf16x4*)&wch[tt * 16 + r][lcol + 16 + g * 4] = pB;
            }
        }
        // preload V for this chunk BEFORE the barrier
        short8 vf[8];
        #pragma unroll
        for (int s = 0; s < 8; ++s)
            vf[s] = *(const short8*)(vrow + ch * 256 + s * 32 + g * 8);

        __syncthreads();   // wch complete

        // phase 3: ds_read + MFMA, 4 t-tiles share each V fragment
        #pragma unroll
        for (int s = 0; s < 8; ++s) {
            #pragma unroll
            for (int tt = 0; tt < 4; ++tt) {
                short8 wf = *(const short8*)&wch[tt * 16 + r][s * 32 + g * 8];
                oacc[tt] = __builtin_amdgcn_mfma_f32_16x16x32_bf16(wf, vf[s], oacc[tt], 0, 0, 0);
            }
        }
        __syncthreads();   // wch reads done before next chunk overwrites
    }

    // C/D (verified r8): oacc[tt][i] = PV[t-local = tt*16 + g*4+i][hd-local = r]
    #pragma unroll
    for (int tt = 0; tt < 4; ++tt)
        for (int i = 0; i < 4; ++i)
            AO[((size_t)(b * TT + t0 + tt * 16 + g * 4 + i)) * DQq + h * HDim + wave * 16 + r] = oacc[tt][i];
}

extern "C" void kernel_launch(void* const* d_in, const int* in_sizes, int n_in,
                              void* d_out, int out_size, void* d_ws, size_t ws_size,
                              hipStream_t stream)
{
    const float* query = (const float*)d_in[0];
    const float* key   = (const float*)d_in[1];
    const float* value = (const float*)d_in[2];
    const int*   kpm   = (const int*)d_in[3];
    const float* amask = (const float*)d_in[4];
    const float* Wq = (const float*)d_in[5];
    const float* bq = (const float*)d_in[6];
    const float* Wk = (const float*)d_in[7];
    const float* bk = (const float*)d_in[8];
    const float* Wv = (const float*)d_in[9];
    const float* bv = (const float*)d_in[10];
    const float* Wo = (const float*)d_in[11];
    const float* bo = (const float*)d_in[12];

    char* ws = (char*)d_ws;
    short* WqT = (short*)ws;  ws += (size_t)512 * 512 * 2;
    short* WkT = (short*)ws;  ws += (size_t)512 * 1024 * 2;
    short* WvT = (short*)ws;  ws += (size_t)512 * 1024 * 2;
    short* WoT = (short*)ws;  ws += (size_t)512 * 512 * 2;
    short* Qh  = (short*)ws;  ws += (size_t)BB * NH * TT * HDim * 2;
    short* Kh  = (short*)ws;  ws += (size_t)BB * NH * SSZ * HDim * 2;
    short* Vth = (short*)ws;  ws += (size_t)BB * NH * HDim * SSZ * 2;
    float* AOf = (float*)ws;  ws += (size_t)BB * TT * DQq * 4;

    float* out0  = (float*)d_out;
    float* attnW = out0 + (size_t)BB * TT * DQq;

    wt_kernel<<<(512*512)/256, 256, 0, stream>>>(Wq, WqT, 512);
    wt_kernel<<<(1024*512)/256, 256, 0, stream>>>(Wk, WkT, 1024);
    wt_kernel<<<(1024*512)/256, 256, 0, stream>>>(Wv, WvT, 1024);
    wt_kernel<<<(512*512)/256, 256, 0, stream>>>(Wo, WoT, 512);

    dim3 gp(8192 / 64, 512 / 64);
    gemm_proj<0, false><<<gp, 256, 0, stream>>>(query, WqT, bq, Qh, 512);
    gemm_proj<0, false><<<gp, 256, 0, stream>>>(key,   WkT, bk, Kh, 1024);
    gemm_proj<1, false><<<gp, 256, 0, stream>>>(value, WvT, bv, Vth, 1024);

    dim3 ga(TT / 64, BB * NH);
    attn_pv<<<ga, 256, 0, stream>>>(Qh, Kh, Vth, kpm, amask, attnW, AOf);

    gemm_proj<2, false><<<gp, 256, 0, stream>>>(AOf, WoT, bo, out0, 512);
}